// Round 9
// baseline (170.577 us; speedup 1.0000x reference)
//
#include <hip/hip_runtime.h>
#include <hip/hip_bf16.h>
#include <math.h>

typedef __attribute__((ext_vector_type(4))) float  f32x4;
typedef __attribute__((ext_vector_type(8))) short  short8;
typedef __attribute__((ext_vector_type(4))) short  short4_t;

#define DTC   0.1f
#define EPSF  1e-6f
// lower-triangle (i>=j) of 64x64: 2080 pairs, padded to 2176 = 17*128 packed cols
#define NPACK 2176
#define NTRI  2080
#define SPLITK 8

static __device__ __forceinline__ unsigned short f2bf(float f) {
    union { float f; unsigned int u; } v; v.f = f;
    unsigned int u = v.u;
    return (unsigned short)((u + 0x7FFFu + ((u >> 16) & 1u)) >> 16);  // RNE
}
static __device__ __forceinline__ unsigned short f2bf_hw(float f) {
    __hip_bfloat16 b = __float2bfloat16(f);
    union { __hip_bfloat16 b; unsigned short u; } v; v.b = b;
    return v.u;
}
static __device__ __forceinline__ float bf2f(unsigned short b) {
    union { unsigned int u; float f; } v; v.u = ((unsigned int)b) << 16;
    return v.f;
}

// ---- fp8 OCP e4m3 (fn): manual RNE encode/decode (frexp/ldexp/rndne are 1-instr)
static __device__ __forceinline__ unsigned char f2fp8(float f) {
    union { float f; unsigned u; } v; v.f = f;
    unsigned s = (v.u >> 24) & 0x80;
    float a = fabsf(f);
    if (a < 1e-8f) return (unsigned char)s;              // zero
    if (!(a < 448.f)) return (unsigned char)(s | 0x7E);  // clamp to max finite
    int e; float m = frexpf(a, &e);        // a = m * 2^e, m in [0.5,1)
    int E = e + 6;                         // biased exp: a = (2m) * 2^(E-7)
    if (E <= 0) {                          // denormal: units of 2^-9
        int q = (int)rintf(a * 512.f);     // 0..8
        if (q >= 8) return (unsigned char)(s | 0x08);
        return (unsigned char)(s | q);
    }
    int q = (int)rintf((2.f * m - 1.f) * 8.f);  // 0..8
    if (q == 8) { E += 1; q = 0; if (E > 15) return (unsigned char)(s | 0x7E); }
    return (unsigned char)(s | (E << 3) | q);
}
static __device__ __forceinline__ float fp82f(unsigned char b) {
    int E = (b >> 3) & 0xF, m = b & 7;
    float mag = E ? ldexpf(1.f + m * 0.125f, E - 7) : ldexpf((float)m, -9);
    return (b & 0x80) ? -mag : mag;
}

// packed index p (0..2079) -> (i,j), i>=j. Row r pairs diag r (len 64-r) with
// diag 63-r (len r+1): 32 rows * 65 = 2080.
static __device__ __forceinline__ void tri_unpack(int p, int& i, int& j) {
    int r = p / 65, c = p - r * 65;
    if (c < 64 - r) { j = c;            i = c + r;       }
    else            { j = c - 64 + r;   i = j + 63 - r;  }
}

static __device__ __forceinline__ void gload_lds16(const void* gptr, void* ldsptr) {
    __builtin_amdgcn_global_load_lds(
        (const __attribute__((address_space(1))) unsigned int*)gptr,
        (__attribute__((address_space(3))) unsigned int*)ldsptr, 16, 0, 0);
}

// ---------------- pack: W1 -> bf16 ; W2/b2 -> lower-tri-packed bf16/f32 rows
__global__ __launch_bounds__(256) void pack_k(const float* __restrict__ W1,
                                              const float* __restrict__ W2,
                                              const float* __restrict__ b2,
                                              unsigned short* __restrict__ w1b,
                                              unsigned short* __restrict__ w2p,
                                              float* __restrict__ b2p) {
    const int bid = blockIdx.x, t = threadIdx.x;
    if (bid < 1024) {                       // W1: 1,048,576 f32 = 262,144 f32x4
        int idx = bid * 256 + t;
        f32x4 v = ((const f32x4*)W1)[idx];
        short4_t o;
        o[0] = (short)f2bf(v[0]); o[1] = (short)f2bf(v[1]);
        o[2] = (short)f2bf(v[2]); o[3] = (short)f2bf(v[3]);
        ((short4_t*)w1b)[idx] = o;
    } else {                                // one block per packed row p
        int p = bid - 1024;                 // 0..2175
        if (p < NTRI) {
            int i, j; tri_unpack(p, i, j);
            w2p[p * 256 + t] = f2bf(W2[(i * 64 + j) * 256L + t]);
            if (t == 0) b2p[p] = b2[i * 64 + j];
        } else {
            w2p[p * 256 + t] = 0;
            if (t == 0) b2p[p] = 0.f;
        }
    }
}

// --------- GEMM1: BM=64, BN=256(full), split-K=8; f32 A cast in staging; fp8 partials
// P[kz][8192,256] = metric[8192, kz*512:+512] @ W1bf[256, same]^T
__global__ __launch_bounds__(256, 2) void gemm1_k(const float* __restrict__ A,
                                                  const unsigned short* __restrict__ B,
                                                  unsigned char* __restrict__ P) {
    __shared__ unsigned short As[64 * 64];    // 8 KB
    __shared__ unsigned short Bs[256 * 64];   // 32 KB
    const int tid  = threadIdx.x;
    const int lane = tid & 63;
    const int w    = tid >> 6;
    const int wm   = w >> 1, wn = w & 1;      // wave tile: 32 rows x 128 cols
    const long bm  = (long)blockIdx.x * 64;
    const int  kz  = blockIdx.y;

    f32x4 acc[2][8];
#pragma unroll
    for (int m = 0; m < 2; m++)
#pragma unroll
        for (int n = 0; n < 8; n++) acc[m][n] = (f32x4){0.f, 0.f, 0.f, 0.f};

    const int rB = tid >> 3;         // 0..31
    const int cB = (tid & 7) * 8;    // bf16 col

    for (int kk = kz * 512; kk < kz * 512 + 512; kk += 64) {
#pragma unroll
        for (int i = 0; i < 8; i++)
            gload_lds16(B + (i * 32 + rB) * 4096L + kk + cB,
                        (char*)Bs + i * 4096 + tid * 16);
#pragma unroll
        for (int i = 0; i < 2; i++) {
            const int row = i * 32 + rB;
            const float* src = A + (bm + row) * 4096L + kk + cB;
            f32x4 a0 = ((const f32x4*)src)[0];
            f32x4 a1 = ((const f32x4*)src)[1];
            short8 ob;
#pragma unroll
            for (int e = 0; e < 4; e++) ob[e]     = (short)f2bf_hw(a0[e]);
#pragma unroll
            for (int e = 0; e < 4; e++) ob[4 + e] = (short)f2bf_hw(a1[e]);
            *(short8*)&As[row * 64 + cB] = ob;
        }
        __syncthreads();

#pragma unroll
        for (int kq = 0; kq < 2; kq++) {
            short8 af0 = *(const short8*)&As[(wm * 32 + 0 * 16 + (lane & 15)) * 64 +
                                             kq * 32 + (lane >> 4) * 8];
            short8 af1 = *(const short8*)&As[(wm * 32 + 1 * 16 + (lane & 15)) * 64 +
                                             kq * 32 + (lane >> 4) * 8];
#pragma unroll
            for (int n = 0; n < 8; n++) {
                short8 bfn = *(const short8*)&Bs[(wn * 128 + n * 16 + (lane & 15)) * 64 +
                                                 kq * 32 + (lane >> 4) * 8];
                acc[0][n] = __builtin_amdgcn_mfma_f32_16x16x32_bf16(af0, bfn, acc[0][n], 0, 0, 0);
                acc[1][n] = __builtin_amdgcn_mfma_f32_16x16x32_bf16(af1, bfn, acc[1][n], 0, 0, 0);
            }
        }
        __syncthreads();
    }

    unsigned char* Pk = P + (long)kz * (8192L * 256);
#pragma unroll
    for (int n = 0; n < 8; n++) {
        long col = wn * 128 + n * 16 + (lane & 15);
#pragma unroll
        for (int m = 0; m < 2; m++)
#pragma unroll
            for (int r = 0; r < 4; r++) {
                long row = bm + wm * 32 + m * 16 + (lane >> 4) * 4 + r;
                Pk[row * 256 + col] = f2fp8(acc[m][n][r]);
            }
    }
}

// --------------------------------- reduce 8 fp8 partials + b1 + tanh -> h (bf16)
__global__ __launch_bounds__(256) void reduce_h_k(const unsigned char* __restrict__ P,
                                                  const float* __restrict__ b1,
                                                  unsigned short* __restrict__ h) {
    const int idx = blockIdx.x * 256 + threadIdx.x;   // 262,144 groups of 8
    float s[8];
#pragma unroll
    for (int e = 0; e < 8; e++) s[e] = 0.f;
#pragma unroll
    for (int kz = 0; kz < SPLITK; kz++) {
        unsigned long long v =
            *(const unsigned long long*)(P + (long)kz * 2097152 + (long)idx * 8);
#pragma unroll
        for (int e = 0; e < 8; e++)
            s[e] += fp82f((unsigned char)((v >> (8 * e)) & 0xFF));
    }
    const int cb = (idx & 31) * 8;
    f32x4 bv0 = *(const f32x4*)(b1 + cb);
    f32x4 bv1 = *(const f32x4*)(b1 + cb + 4);
    short8 o;
#pragma unroll
    for (int e = 0; e < 4; e++) o[e]     = (short)f2bf(tanhf(s[e] + bv0[e]));
#pragma unroll
    for (int e = 0; e < 4; e++) o[4 + e] = (short)f2bf(tanhf(s[4 + e] + bv1[e]));
    ((short8*)h)[idx] = o;
}

// ------------------- GEMM2 packed: mlpP[8192,2176] = h @ W2p^T + b2p -> fp8
// BM=128, BN=128, BK=64
__global__ __launch_bounds__(256, 2) void gemm2p_k(const unsigned short* __restrict__ A,
                                                   const unsigned short* __restrict__ B,
                                                   const float* __restrict__ bias,
                                                   unsigned char* __restrict__ C) {
    __shared__ unsigned short As[128 * 64];
    __shared__ unsigned short Bs[128 * 64];
    const int tid  = threadIdx.x;
    const int lane = tid & 63;
    const int w    = tid >> 6;
    const int wm   = w >> 1, wn = w & 1;
    const long bm  = (long)blockIdx.x * 128;
    const long bn  = (long)blockIdx.y * 128;   // < 2176

    f32x4 acc[4][4];
#pragma unroll
    for (int m = 0; m < 4; m++)
#pragma unroll
        for (int n = 0; n < 4; n++) acc[m][n] = (f32x4){0.f, 0.f, 0.f, 0.f};

    const int r0 = tid >> 3;
    const int c0 = (tid & 7) * 8;

    for (int kk = 0; kk < 256; kk += 64) {
#pragma unroll
        for (int i = 0; i < 4; i++) {
            gload_lds16(A + (bm + i * 32 + r0) * 256L + kk + c0,
                        (char*)As + i * 4096 + tid * 16);
            gload_lds16(B + (bn + i * 32 + r0) * 256L + kk + c0,
                        (char*)Bs + i * 4096 + tid * 16);
        }
        __syncthreads();

        short8 af[4][2], bf[4][2];
#pragma unroll
        for (int m = 0; m < 4; m++)
#pragma unroll
            for (int kq = 0; kq < 2; kq++)
                af[m][kq] = *(const short8*)&As[(wm * 64 + m * 16 + (lane & 15)) * 64 +
                                                kq * 32 + (lane >> 4) * 8];
#pragma unroll
        for (int n = 0; n < 4; n++)
#pragma unroll
            for (int kq = 0; kq < 2; kq++)
                bf[n][kq] = *(const short8*)&Bs[(wn * 64 + n * 16 + (lane & 15)) * 64 +
                                                kq * 32 + (lane >> 4) * 8];
#pragma unroll
        for (int m = 0; m < 4; m++)
#pragma unroll
            for (int n = 0; n < 4; n++) {
                acc[m][n] = __builtin_amdgcn_mfma_f32_16x16x32_bf16(af[m][0], bf[n][0],
                                                                    acc[m][n], 0, 0, 0);
                acc[m][n] = __builtin_amdgcn_mfma_f32_16x16x32_bf16(af[m][1], bf[n][1],
                                                                    acc[m][n], 0, 0, 0);
            }
        __syncthreads();
    }

#pragma unroll
    for (int n = 0; n < 4; n++) {
        long col = bn + wn * 64 + n * 16 + (lane & 15);
        float bv = bias[col];
#pragma unroll
        for (int m = 0; m < 4; m++)
#pragma unroll
            for (int r = 0; r < 4; r++) {
                long row = bm + wm * 64 + m * 16 + (lane >> 4) * 4 + r;
                C[row * NPACK + col] = f2fp8(acc[m][n][r] + bv);
            }
    }
}

// ---- finalize: scatter packed fp8 mlp -> tri LDS; norms -> adt; out = metric+adt*F
__global__ __launch_bounds__(256) void finalize3_k(const float* __restrict__ metric,
                                                   const float* __restrict__ ricci,
                                                   const unsigned char* __restrict__ mlpP,
                                                   float* __restrict__ out) {
    const int b = blockIdx.x;
    const int t = threadIdx.x;
    const long mbase = (long)b * 4096;
    __shared__ float s_f[64 * 65];  // lower-tri values live at [i*65 + j], j<=i
    __shared__ float red[8];
    __shared__ float s_adt;

    // phase 1: scatter packed mlp (fp8) into s_f
    const unsigned char* mp = mlpP + (long)b * NPACK;
    {
        unsigned long long v = *(const unsigned long long*)(mp + t * 8);
#pragma unroll
        for (int e = 0; e < 8; e++) {
            int p = t * 8 + e, i, j;
            tri_unpack(p, i, j);
            s_f[i * 65 + j] = fp82f((unsigned char)((v >> (8 * e)) & 0xFF));
        }
        if (t < 4) {                             // p = 2048 .. 2079
            unsigned long long v2 = *(const unsigned long long*)(mp + 2048 + t * 8);
#pragma unroll
            for (int e = 0; e < 8; e++) {
                int p = 2048 + t * 8 + e, i, j;
                tri_unpack(p, i, j);
                s_f[i * 65 + j] = fp82f((unsigned char)((v2 >> (8 * e)) & 0xFF));
            }
        }
    }
    __syncthreads();

    // phase 2: norms + fold -2*ricci into lower-tri slots (unique owner per slot)
    const f32x4* met4 = (const f32x4*)(metric + mbase);
    const f32x4* ric4 = (const f32x4*)(ricci + mbase);
    f32x4 mm[4];
    float msq = 0.f, rsq = 0.f;
#pragma unroll
    for (int k = 0; k < 4; k++) {
        int v = k * 256 + t;
        f32x4 r = ric4[v];
        f32x4 m = met4[v];
        mm[k] = m;
        msq += m[0]*m[0] + m[1]*m[1] + m[2]*m[2] + m[3]*m[3];
        rsq += r[0]*r[0] + r[1]*r[1] + r[2]*r[2] + r[3]*r[3];
        int e0 = v * 4;
        int i = e0 >> 6, j0 = e0 & 63;
#pragma unroll
        for (int e = 0; e < 4; e++) {
            int j = j0 + e;
            if (j <= i) s_f[i * 65 + j] -= 2.f * r[e];
        }
    }
#pragma unroll
    for (int off = 32; off > 0; off >>= 1) {
        msq += __shfl_down(msq, off);
        rsq += __shfl_down(rsq, off);
    }
    if ((t & 63) == 0) { red[t >> 6] = msq; red[4 + (t >> 6)] = rsq; }
    __syncthreads();
    if (t == 0) {
        float tm = red[0] + red[1] + red[2] + red[3];
        float tr = red[4] + red[5] + red[6] + red[7];
        s_adt = DTC * fminf(1.0f, 0.1f * sqrtf(tm) / (sqrtf(tr) + EPSF));
    }
    __syncthreads();

    // phase 3: out = metric + adt * F[max][min]  (nontemporal store)
    const float adt = s_adt;
    f32x4* out4 = (f32x4*)(out + mbase);
#pragma unroll
    for (int k = 0; k < 4; k++) {
        int v = k * 256 + t;
        int e0 = v * 4;
        int i = e0 >> 6, j0 = e0 & 63;
        f32x4 o;
#pragma unroll
        for (int e = 0; e < 4; e++) {
            int j = j0 + e;
            int mx = i > j ? i : j;
            int mn = i > j ? j : i;
            o[e] = mm[k][e] + adt * s_f[mx * 65 + mn];
        }
        __builtin_nontemporal_store(o, &out4[v]);
    }
}

// ---------------------------------------------------------------------- launcher
extern "C" void kernel_launch(void* const* d_in, const int* in_sizes, int n_in,
                              void* d_out, int out_size, void* d_ws, size_t ws_size,
                              hipStream_t stream) {
    const float* metric = (const float*)d_in[0];  // [8192,64,64]
    const float* ricci  = (const float*)d_in[1];  // [8192,64,64]
    const float* W1     = (const float*)d_in[2];  // [256,4096]
    const float* b1     = (const float*)d_in[3];  // [256]
    const float* W2     = (const float*)d_in[4];  // [4096,256]
    const float* b2     = (const float*)d_in[5];  // [4096]
    float* out = (float*)d_out;

    const int B = 8192;

    char* ws = (char*)d_ws;
    unsigned char*  mlpP = (unsigned char*)(ws);                 // 8192*2176   = 17,825,792
    unsigned short* w1b  = (unsigned short*)(ws + 17825792);     // 2,097,152
    unsigned short* w2p  = (unsigned short*)(ws + 19922944);     // 2176*256*2  = 1,114,112
    float*          b2p  = (float*)(ws + 21037056);              // 2176*4      = 8,704
    unsigned short* hbf  = (unsigned short*)(ws + 21045760);     // 8192*256*2  = 4,194,304
    // split-K fp8 partials live in d_out (dead until finalize): 8*8192*256 = 16.8 MB
    unsigned char* part = (unsigned char*)out;

    // pack/cast weights (W1 cast: blocks 0..1023; W2/b2 tri-pack: blocks 1024..3199)
    pack_k<<<dim3(1024 + NPACK), dim3(256), 0, stream>>>(W1, W2, b2, w1b, w2p, b2p);

    // GEMM1: BM=64 x BN=256(full) x split-K=8 -> fp8 partials in d_out (4 blocks/CU)
    gemm1_k<<<dim3(B / 64, SPLITK), dim3(256), 0, stream>>>(metric, w1b, part);
    // h = tanh(sum partials + b1) -> bf16
    reduce_h_k<<<dim3(B * 256 / 8 / 256), dim3(256), 0, stream>>>(part, b1, hbf);
    // mlpP = h @ W2p^T + b2p -> fp8 packed lower-tri columns
    gemm2p_k<<<dim3(B / 128, NPACK / 128), dim3(256), 0, stream>>>(hbf, w2p, b2p, mlpP);
    // out = metric + adt * sym_lower(-2*ricci + mlp)
    finalize3_k<<<dim3(B), dim3(256), 0, stream>>>(metric, ricci, mlpP, out);

    (void)in_sizes; (void)n_in; (void)out_size; (void)ws_size;
}

// Round 10
// 129.938 us; speedup vs baseline: 1.3128x; 1.3128x over previous
//
#include <hip/hip_runtime.h>
#include <hip/hip_bf16.h>
#include <math.h>

typedef __attribute__((ext_vector_type(4))) float  f32x4;
typedef __attribute__((ext_vector_type(2))) float  f32x2;
typedef __attribute__((ext_vector_type(8))) short  short8;
typedef __attribute__((ext_vector_type(4))) short  short4_t;

#define DTC   0.1f
#define EPSF  1e-6f
// lower-triangle (i>=j) of 64x64: 2080 pairs, padded to 2176 = 17*128 packed cols
#define NPACK 2176
#define NTRI  2080
#define SPLITK 8

static __device__ __forceinline__ unsigned short f2bf(float f) {
    union { float f; unsigned int u; } v; v.f = f;
    unsigned int u = v.u;
    return (unsigned short)((u + 0x7FFFu + ((u >> 16) & 1u)) >> 16);  // RNE
}
static __device__ __forceinline__ unsigned short f2bf_hw(float f) {
    __hip_bfloat16 b = __float2bfloat16(f);
    union { __hip_bfloat16 b; unsigned short u; } v; v.b = b;
    return v.u;
}
static __device__ __forceinline__ float bf2f(unsigned short b) {
    union { unsigned int u; float f; } v; v.u = ((unsigned int)b) << 16;
    return v.f;
}

// ---- fp8 OCP e4m3 via gfx950 HW packed converters (1 instr / 2 values, RNE+sat)
static __device__ __forceinline__ unsigned int cvt2_fp8(float a, float b) {
    unsigned int r = 0;
    asm("v_cvt_pk_fp8_f32 %0, %1, %2" : "+v"(r) : "v"(a), "v"(b));
    return r;   // byte0 = fp8(a), byte1 = fp8(b)
}
static __device__ __forceinline__ f32x2 fp8x2_f32(unsigned int packed /* low 16 bits */) {
    f32x2 d;
    asm("v_cvt_pk_f32_fp8 %0, %1" : "=v"(d) : "v"(packed));
    return d;   // d[0] = byte0, d[1] = byte1
}

// packed index p (0..2079) -> (i,j), i>=j. Row r pairs diag r (len 64-r) with
// diag 63-r (len r+1): 32 rows * 65 = 2080.
static __device__ __forceinline__ void tri_unpack(int p, int& i, int& j) {
    int r = p / 65, c = p - r * 65;
    if (c < 64 - r) { j = c;            i = c + r;       }
    else            { j = c - 64 + r;   i = j + 63 - r;  }
}

static __device__ __forceinline__ void gload_lds16(const void* gptr, void* ldsptr) {
    __builtin_amdgcn_global_load_lds(
        (const __attribute__((address_space(1))) unsigned int*)gptr,
        (__attribute__((address_space(3))) unsigned int*)ldsptr, 16, 0, 0);
}

// ---------------- pack: W1 -> bf16 ; W2/b2 -> lower-tri-packed bf16/f32 rows
__global__ __launch_bounds__(256) void pack_k(const float* __restrict__ W1,
                                              const float* __restrict__ W2,
                                              const float* __restrict__ b2,
                                              unsigned short* __restrict__ w1b,
                                              unsigned short* __restrict__ w2p,
                                              float* __restrict__ b2p) {
    const int bid = blockIdx.x, t = threadIdx.x;
    if (bid < 1024) {                       // W1: 1,048,576 f32 = 262,144 f32x4
        int idx = bid * 256 + t;
        f32x4 v = ((const f32x4*)W1)[idx];
        short4_t o;
        o[0] = (short)f2bf(v[0]); o[1] = (short)f2bf(v[1]);
        o[2] = (short)f2bf(v[2]); o[3] = (short)f2bf(v[3]);
        ((short4_t*)w1b)[idx] = o;
    } else {                                // one block per packed row p
        int p = bid - 1024;                 // 0..2175
        if (p < NTRI) {
            int i, j; tri_unpack(p, i, j);
            w2p[p * 256 + t] = f2bf(W2[(i * 64 + j) * 256L + t]);
            if (t == 0) b2p[p] = b2[i * 64 + j];
        } else {
            w2p[p * 256 + t] = 0;
            if (t == 0) b2p[p] = 0.f;
        }
    }
}

// --------- GEMM1: BM=64, BN=256(full), split-K=8; f32 A cast in staging; fp8 partials
// P[kz][8192,256] = metric[8192, kz*512:+512] @ W1bf[256, same]^T
__global__ __launch_bounds__(256, 2) void gemm1_k(const float* __restrict__ A,
                                                  const unsigned short* __restrict__ B,
                                                  unsigned char* __restrict__ P) {
    __shared__ unsigned short As[64 * 64];    // 8 KB
    __shared__ unsigned short Bs[256 * 64];   // 32 KB
    const int tid  = threadIdx.x;
    const int lane = tid & 63;
    const int w    = tid >> 6;
    const int wm   = w >> 1, wn = w & 1;      // wave tile: 32 rows x 128 cols
    const long bm  = (long)blockIdx.x * 64;
    const int  kz  = blockIdx.y;

    f32x4 acc[2][8];
#pragma unroll
    for (int m = 0; m < 2; m++)
#pragma unroll
        for (int n = 0; n < 8; n++) acc[m][n] = (f32x4){0.f, 0.f, 0.f, 0.f};

    const int rB = tid >> 3;         // 0..31
    const int cB = (tid & 7) * 8;    // bf16 col

    for (int kk = kz * 512; kk < kz * 512 + 512; kk += 64) {
#pragma unroll
        for (int i = 0; i < 8; i++)
            gload_lds16(B + (i * 32 + rB) * 4096L + kk + cB,
                        (char*)Bs + i * 4096 + tid * 16);
#pragma unroll
        for (int i = 0; i < 2; i++) {
            const int row = i * 32 + rB;
            const float* src = A + (bm + row) * 4096L + kk + cB;
            f32x4 a0 = ((const f32x4*)src)[0];
            f32x4 a1 = ((const f32x4*)src)[1];
            short8 ob;
#pragma unroll
            for (int e = 0; e < 4; e++) ob[e]     = (short)f2bf_hw(a0[e]);
#pragma unroll
            for (int e = 0; e < 4; e++) ob[4 + e] = (short)f2bf_hw(a1[e]);
            *(short8*)&As[row * 64 + cB] = ob;
        }
        __syncthreads();

#pragma unroll
        for (int kq = 0; kq < 2; kq++) {
            short8 af0 = *(const short8*)&As[(wm * 32 + 0 * 16 + (lane & 15)) * 64 +
                                             kq * 32 + (lane >> 4) * 8];
            short8 af1 = *(const short8*)&As[(wm * 32 + 1 * 16 + (lane & 15)) * 64 +
                                             kq * 32 + (lane >> 4) * 8];
#pragma unroll
            for (int n = 0; n < 8; n++) {
                short8 bfn = *(const short8*)&Bs[(wn * 128 + n * 16 + (lane & 15)) * 64 +
                                                 kq * 32 + (lane >> 4) * 8];
                acc[0][n] = __builtin_amdgcn_mfma_f32_16x16x32_bf16(af0, bfn, acc[0][n], 0, 0, 0);
                acc[1][n] = __builtin_amdgcn_mfma_f32_16x16x32_bf16(af1, bfn, acc[1][n], 0, 0, 0);
            }
        }
        __syncthreads();
    }

    unsigned char* Pk = P + (long)kz * (8192L * 256);
#pragma unroll
    for (int n = 0; n < 8; n++) {
        long col = wn * 128 + n * 16 + (lane & 15);
#pragma unroll
        for (int m = 0; m < 2; m++) {
            unsigned int p01 = cvt2_fp8(acc[m][n][0], acc[m][n][1]);
            unsigned int p23 = cvt2_fp8(acc[m][n][2], acc[m][n][3]);
            long row = bm + wm * 32 + m * 16 + (lane >> 4) * 4;
            Pk[(row + 0) * 256 + col] = (unsigned char)(p01 & 0xFF);
            Pk[(row + 1) * 256 + col] = (unsigned char)((p01 >> 8) & 0xFF);
            Pk[(row + 2) * 256 + col] = (unsigned char)(p23 & 0xFF);
            Pk[(row + 3) * 256 + col] = (unsigned char)((p23 >> 8) & 0xFF);
        }
    }
}

// --------------------------------- reduce 8 fp8 partials + b1 + tanh -> h (bf16)
__global__ __launch_bounds__(256) void reduce_h_k(const unsigned char* __restrict__ P,
                                                  const float* __restrict__ b1,
                                                  unsigned short* __restrict__ h) {
    const int idx = blockIdx.x * 256 + threadIdx.x;   // 262,144 groups of 8
    float s[8];
#pragma unroll
    for (int e = 0; e < 8; e++) s[e] = 0.f;
#pragma unroll
    for (int kz = 0; kz < SPLITK; kz++) {
        unsigned long long v =
            *(const unsigned long long*)(P + (long)kz * 2097152 + (long)idx * 8);
#pragma unroll
        for (int q = 0; q < 4; q++) {
            f32x2 d = fp8x2_f32((unsigned int)((v >> (16 * q)) & 0xFFFF));
            s[2 * q]     += d[0];
            s[2 * q + 1] += d[1];
        }
    }
    const int cb = (idx & 31) * 8;
    f32x4 bv0 = *(const f32x4*)(b1 + cb);
    f32x4 bv1 = *(const f32x4*)(b1 + cb + 4);
    short8 o;
#pragma unroll
    for (int e = 0; e < 4; e++) o[e]     = (short)f2bf(tanhf(s[e] + bv0[e]));
#pragma unroll
    for (int e = 0; e < 4; e++) o[4 + e] = (short)f2bf(tanhf(s[4 + e] + bv1[e]));
    ((short8*)h)[idx] = o;
}

// ------------------- GEMM2 packed: mlpP[8192,2176] = h @ W2p^T + b2p -> fp8
// BM=128, BN=128, BK=64
__global__ __launch_bounds__(256, 2) void gemm2p_k(const unsigned short* __restrict__ A,
                                                   const unsigned short* __restrict__ B,
                                                   const float* __restrict__ bias,
                                                   unsigned char* __restrict__ C) {
    __shared__ unsigned short As[128 * 64];
    __shared__ unsigned short Bs[128 * 64];
    const int tid  = threadIdx.x;
    const int lane = tid & 63;
    const int w    = tid >> 6;
    const int wm   = w >> 1, wn = w & 1;
    const long bm  = (long)blockIdx.x * 128;
    const long bn  = (long)blockIdx.y * 128;   // < 2176

    f32x4 acc[4][4];
#pragma unroll
    for (int m = 0; m < 4; m++)
#pragma unroll
        for (int n = 0; n < 4; n++) acc[m][n] = (f32x4){0.f, 0.f, 0.f, 0.f};

    const int r0 = tid >> 3;
    const int c0 = (tid & 7) * 8;

    for (int kk = 0; kk < 256; kk += 64) {
#pragma unroll
        for (int i = 0; i < 4; i++) {
            gload_lds16(A + (bm + i * 32 + r0) * 256L + kk + c0,
                        (char*)As + i * 4096 + tid * 16);
            gload_lds16(B + (bn + i * 32 + r0) * 256L + kk + c0,
                        (char*)Bs + i * 4096 + tid * 16);
        }
        __syncthreads();

        short8 af[4][2], bf[4][2];
#pragma unroll
        for (int m = 0; m < 4; m++)
#pragma unroll
            for (int kq = 0; kq < 2; kq++)
                af[m][kq] = *(const short8*)&As[(wm * 64 + m * 16 + (lane & 15)) * 64 +
                                                kq * 32 + (lane >> 4) * 8];
#pragma unroll
        for (int n = 0; n < 4; n++)
#pragma unroll
            for (int kq = 0; kq < 2; kq++)
                bf[n][kq] = *(const short8*)&Bs[(wn * 64 + n * 16 + (lane & 15)) * 64 +
                                                kq * 32 + (lane >> 4) * 8];
#pragma unroll
        for (int m = 0; m < 4; m++)
#pragma unroll
            for (int n = 0; n < 4; n++) {
                acc[m][n] = __builtin_amdgcn_mfma_f32_16x16x32_bf16(af[m][0], bf[n][0],
                                                                    acc[m][n], 0, 0, 0);
                acc[m][n] = __builtin_amdgcn_mfma_f32_16x16x32_bf16(af[m][1], bf[n][1],
                                                                    acc[m][n], 0, 0, 0);
            }
        __syncthreads();
    }

#pragma unroll
    for (int n = 0; n < 4; n++) {
        long col = bn + wn * 64 + n * 16 + (lane & 15);
        float bv = bias[col];
#pragma unroll
        for (int m = 0; m < 4; m++) {
            unsigned int p01 = cvt2_fp8(acc[m][n][0] + bv, acc[m][n][1] + bv);
            unsigned int p23 = cvt2_fp8(acc[m][n][2] + bv, acc[m][n][3] + bv);
            long row = bm + wm * 64 + m * 16 + (lane >> 4) * 4;
            C[(row + 0) * NPACK + col] = (unsigned char)(p01 & 0xFF);
            C[(row + 1) * NPACK + col] = (unsigned char)((p01 >> 8) & 0xFF);
            C[(row + 2) * NPACK + col] = (unsigned char)(p23 & 0xFF);
            C[(row + 3) * NPACK + col] = (unsigned char)((p23 >> 8) & 0xFF);
        }
    }
}

// ---- finalize: scatter packed fp8 mlp -> tri LDS; norms -> adt; out = metric+adt*F
__global__ __launch_bounds__(256) void finalize3_k(const float* __restrict__ metric,
                                                   const float* __restrict__ ricci,
                                                   const unsigned char* __restrict__ mlpP,
                                                   float* __restrict__ out) {
    const int b = blockIdx.x;
    const int t = threadIdx.x;
    const long mbase = (long)b * 4096;
    __shared__ float s_f[64 * 65];  // lower-tri values live at [i*65 + j], j<=i
    __shared__ float red[8];
    __shared__ float s_adt;

    // phase 1: scatter packed mlp (fp8, HW decode) into s_f
    const unsigned char* mp = mlpP + (long)b * NPACK;
    {
        unsigned long long v = *(const unsigned long long*)(mp + t * 8);
#pragma unroll
        for (int q = 0; q < 4; q++) {
            f32x2 d = fp8x2_f32((unsigned int)((v >> (16 * q)) & 0xFFFF));
#pragma unroll
            for (int e = 0; e < 2; e++) {
                int p = t * 8 + 2 * q + e, i, j;
                tri_unpack(p, i, j);
                s_f[i * 65 + j] = d[e];
            }
        }
        if (t < 4) {                             // p = 2048 .. 2079
            unsigned long long v2 = *(const unsigned long long*)(mp + 2048 + t * 8);
#pragma unroll
            for (int q = 0; q < 4; q++) {
                f32x2 d = fp8x2_f32((unsigned int)((v2 >> (16 * q)) & 0xFFFF));
#pragma unroll
                for (int e = 0; e < 2; e++) {
                    int p = 2048 + t * 8 + 2 * q + e, i, j;
                    tri_unpack(p, i, j);
                    s_f[i * 65 + j] = d[e];
                }
            }
        }
    }
    __syncthreads();

    // phase 2: norms + fold -2*ricci into lower-tri slots (unique owner per slot)
    const f32x4* met4 = (const f32x4*)(metric + mbase);
    const f32x4* ric4 = (const f32x4*)(ricci + mbase);
    f32x4 mm[4];
    float msq = 0.f, rsq = 0.f;
#pragma unroll
    for (int k = 0; k < 4; k++) {
        int v = k * 256 + t;
        f32x4 r = ric4[v];
        f32x4 m = met4[v];
        mm[k] = m;
        msq += m[0]*m[0] + m[1]*m[1] + m[2]*m[2] + m[3]*m[3];
        rsq += r[0]*r[0] + r[1]*r[1] + r[2]*r[2] + r[3]*r[3];
        int e0 = v * 4;
        int i = e0 >> 6, j0 = e0 & 63;
#pragma unroll
        for (int e = 0; e < 4; e++) {
            int j = j0 + e;
            if (j <= i) s_f[i * 65 + j] -= 2.f * r[e];
        }
    }
#pragma unroll
    for (int off = 32; off > 0; off >>= 1) {
        msq += __shfl_down(msq, off);
        rsq += __shfl_down(rsq, off);
    }
    if ((t & 63) == 0) { red[t >> 6] = msq; red[4 + (t >> 6)] = rsq; }
    __syncthreads();
    if (t == 0) {
        float tm = red[0] + red[1] + red[2] + red[3];
        float tr = red[4] + red[5] + red[6] + red[7];
        s_adt = DTC * fminf(1.0f, 0.1f * sqrtf(tm) / (sqrtf(tr) + EPSF));
    }
    __syncthreads();

    // phase 3: out = metric + adt * F[max][min]  (nontemporal store)
    const float adt = s_adt;
    f32x4* out4 = (f32x4*)(out + mbase);
#pragma unroll
    for (int k = 0; k < 4; k++) {
        int v = k * 256 + t;
        int e0 = v * 4;
        int i = e0 >> 6, j0 = e0 & 63;
        f32x4 o;
#pragma unroll
        for (int e = 0; e < 4; e++) {
            int j = j0 + e;
            int mx = i > j ? i : j;
            int mn = i > j ? j : i;
            o[e] = mm[k][e] + adt * s_f[mx * 65 + mn];
        }
        __builtin_nontemporal_store(o, &out4[v]);
    }
}

// ---------------------------------------------------------------------- launcher
extern "C" void kernel_launch(void* const* d_in, const int* in_sizes, int n_in,
                              void* d_out, int out_size, void* d_ws, size_t ws_size,
                              hipStream_t stream) {
    const float* metric = (const float*)d_in[0];  // [8192,64,64]
    const float* ricci  = (const float*)d_in[1];  // [8192,64,64]
    const float* W1     = (const float*)d_in[2];  // [256,4096]
    const float* b1     = (const float*)d_in[3];  // [256]
    const float* W2     = (const float*)d_in[4];  // [4096,256]
    const float* b2     = (const float*)d_in[5];  // [4096]
    float* out = (float*)d_out;

    const int B = 8192;

    char* ws = (char*)d_ws;
    unsigned char*  mlpP = (unsigned char*)(ws);                 // 8192*2176   = 17,825,792
    unsigned short* w1b  = (unsigned short*)(ws + 17825792);     // 2,097,152
    unsigned short* w2p  = (unsigned short*)(ws + 19922944);     // 2176*256*2  = 1,114,112
    float*          b2p  = (float*)(ws + 21037056);              // 2176*4      = 8,704
    unsigned short* hbf  = (unsigned short*)(ws + 21045760);     // 8192*256*2  = 4,194,304
    // split-K fp8 partials live in d_out (dead until finalize): 8*8192*256 = 16.8 MB
    unsigned char* part = (unsigned char*)out;

    // pack/cast weights (W1 cast: blocks 0..1023; W2/b2 tri-pack: blocks 1024..3199)
    pack_k<<<dim3(1024 + NPACK), dim3(256), 0, stream>>>(W1, W2, b2, w1b, w2p, b2p);

    // GEMM1: BM=64 x BN=256(full) x split-K=8 -> fp8 partials in d_out (4 blocks/CU)
    gemm1_k<<<dim3(B / 64, SPLITK), dim3(256), 0, stream>>>(metric, w1b, part);
    // h = tanh(sum partials + b1) -> bf16
    reduce_h_k<<<dim3(B * 256 / 8 / 256), dim3(256), 0, stream>>>(part, b1, hbf);
    // mlpP = h @ W2p^T + b2p -> fp8 packed lower-tri columns
    gemm2p_k<<<dim3(B / 128, NPACK / 128), dim3(256), 0, stream>>>(hbf, w2p, b2p, mlpP);
    // out = metric + adt * sym_lower(-2*ricci + mlp)
    finalize3_k<<<dim3(B), dim3(256), 0, stream>>>(metric, ricci, mlpP, out);

    (void)in_sizes; (void)n_in; (void)out_size; (void)ws_size;
}

// Round 11
// 129.322 us; speedup vs baseline: 1.3190x; 1.0048x over previous
//
#include <hip/hip_runtime.h>
#include <hip/hip_bf16.h>
#include <math.h>

typedef __attribute__((ext_vector_type(4))) float  f32x4;
typedef __attribute__((ext_vector_type(2))) float  f32x2;
typedef __attribute__((ext_vector_type(8))) short  short8;
typedef __attribute__((ext_vector_type(4))) short  short4_t;

#define DTC   0.1f
#define EPSF  1e-6f
// lower-triangle (i>=j) of 64x64: 2080 pairs, padded to 2176 = 17*128 packed cols
#define NPACK 2176
#define NTRI  2080
#define SPLITK 8

static __device__ __forceinline__ unsigned short f2bf(float f) {
    union { float f; unsigned int u; } v; v.f = f;
    unsigned int u = v.u;
    return (unsigned short)((u + 0x7FFFu + ((u >> 16) & 1u)) >> 16);  // RNE
}
static __device__ __forceinline__ unsigned short f2bf_hw(float f) {
    __hip_bfloat16 b = __float2bfloat16(f);
    union { __hip_bfloat16 b; unsigned short u; } v; v.b = b;
    return v.u;
}
static __device__ __forceinline__ float bf2f(unsigned short b) {
    union { unsigned int u; float f; } v; v.u = ((unsigned int)b) << 16;
    return v.f;
}

// ---- fp8 OCP e4m3 via gfx950 HW packed converters (1 instr / 2 values, RNE+sat)
static __device__ __forceinline__ unsigned int cvt2_fp8(float a, float b) {
    unsigned int r = 0;
    asm("v_cvt_pk_fp8_f32 %0, %1, %2" : "+v"(r) : "v"(a), "v"(b));
    return r;   // byte0 = fp8(a), byte1 = fp8(b)
}
static __device__ __forceinline__ f32x2 fp8x2_f32(unsigned int packed /* low 16 bits */) {
    f32x2 d;
    asm("v_cvt_pk_f32_fp8 %0, %1" : "=v"(d) : "v"(packed));
    return d;   // d[0] = byte0, d[1] = byte1
}

// packed index p (0..2079) -> (i,j), i>=j. Row r pairs diag r (len 64-r) with
// diag 63-r (len r+1): 32 rows * 65 = 2080.
static __device__ __forceinline__ void tri_unpack(int p, int& i, int& j) {
    int r = p / 65, c = p - r * 65;
    if (c < 64 - r) { j = c;            i = c + r;       }
    else            { j = c - 64 + r;   i = j + 63 - r;  }
}

static __device__ __forceinline__ void gload_lds16(const void* gptr, void* ldsptr) {
    __builtin_amdgcn_global_load_lds(
        (const __attribute__((address_space(1))) unsigned int*)gptr,
        (__attribute__((address_space(3))) unsigned int*)ldsptr, 16, 0, 0);
}

// ---------------- pack: W1 -> bf16 ; W2/b2 -> lower-tri-packed bf16/f32 rows
__global__ __launch_bounds__(256) void pack_k(const float* __restrict__ W1,
                                              const float* __restrict__ W2,
                                              const float* __restrict__ b2,
                                              unsigned short* __restrict__ w1b,
                                              unsigned short* __restrict__ w2p,
                                              float* __restrict__ b2p) {
    const int bid = blockIdx.x, t = threadIdx.x;
    if (bid < 1024) {                       // W1: 1,048,576 f32 = 262,144 f32x4
        int idx = bid * 256 + t;
        f32x4 v = ((const f32x4*)W1)[idx];
        short4_t o;
        o[0] = (short)f2bf(v[0]); o[1] = (short)f2bf(v[1]);
        o[2] = (short)f2bf(v[2]); o[3] = (short)f2bf(v[3]);
        ((short4_t*)w1b)[idx] = o;
    } else {                                // one block per packed row p
        int p = bid - 1024;                 // 0..2175
        if (p < NTRI) {
            int i, j; tri_unpack(p, i, j);
            w2p[p * 256 + t] = f2bf(W2[(i * 64 + j) * 256L + t]);
            if (t == 0) b2p[p] = b2[i * 64 + j];
        } else {
            w2p[p * 256 + t] = 0;
            if (t == 0) b2p[p] = 0.f;
        }
    }
}

// --------- GEMM1: BM=64, BN=256(full), split-K=8; f32 A cast in staging; fp8 partials
// P[kz][8192,256] = metric[8192, kz*512:+512] @ W1bf[256, same]^T
__global__ __launch_bounds__(256, 2) void gemm1_k(const float* __restrict__ A,
                                                  const unsigned short* __restrict__ B,
                                                  unsigned char* __restrict__ P) {
    __shared__ unsigned short As[64 * 64];    // 8 KB
    __shared__ unsigned short Bs[256 * 64];   // 32 KB
    const int tid  = threadIdx.x;
    const int lane = tid & 63;
    const int w    = tid >> 6;
    const int wm   = w >> 1, wn = w & 1;      // wave tile: 32 rows x 128 cols
    const long bm  = (long)blockIdx.x * 64;
    const int  kz  = blockIdx.y;

    f32x4 acc[2][8];
#pragma unroll
    for (int m = 0; m < 2; m++)
#pragma unroll
        for (int n = 0; n < 8; n++) acc[m][n] = (f32x4){0.f, 0.f, 0.f, 0.f};

    const int rB = tid >> 3;         // 0..31
    const int cB = (tid & 7) * 8;    // bf16 col

    for (int kk = kz * 512; kk < kz * 512 + 512; kk += 64) {
#pragma unroll
        for (int i = 0; i < 8; i++)
            gload_lds16(B + (i * 32 + rB) * 4096L + kk + cB,
                        (char*)Bs + i * 4096 + tid * 16);
#pragma unroll
        for (int i = 0; i < 2; i++) {
            const int row = i * 32 + rB;
            const float* src = A + (bm + row) * 4096L + kk + cB;
            f32x4 a0 = ((const f32x4*)src)[0];
            f32x4 a1 = ((const f32x4*)src)[1];
            short8 ob;
#pragma unroll
            for (int e = 0; e < 4; e++) ob[e]     = (short)f2bf_hw(a0[e]);
#pragma unroll
            for (int e = 0; e < 4; e++) ob[4 + e] = (short)f2bf_hw(a1[e]);
            *(short8*)&As[row * 64 + cB] = ob;
        }
        __syncthreads();

#pragma unroll
        for (int kq = 0; kq < 2; kq++) {
            short8 af0 = *(const short8*)&As[(wm * 32 + 0 * 16 + (lane & 15)) * 64 +
                                             kq * 32 + (lane >> 4) * 8];
            short8 af1 = *(const short8*)&As[(wm * 32 + 1 * 16 + (lane & 15)) * 64 +
                                             kq * 32 + (lane >> 4) * 8];
#pragma unroll
            for (int n = 0; n < 8; n++) {
                short8 bfn = *(const short8*)&Bs[(wn * 128 + n * 16 + (lane & 15)) * 64 +
                                                 kq * 32 + (lane >> 4) * 8];
                acc[0][n] = __builtin_amdgcn_mfma_f32_16x16x32_bf16(af0, bfn, acc[0][n], 0, 0, 0);
                acc[1][n] = __builtin_amdgcn_mfma_f32_16x16x32_bf16(af1, bfn, acc[1][n], 0, 0, 0);
            }
        }
        __syncthreads();
    }

    unsigned char* Pk = P + (long)kz * (8192L * 256);
#pragma unroll
    for (int n = 0; n < 8; n++) {
        long col = wn * 128 + n * 16 + (lane & 15);
#pragma unroll
        for (int m = 0; m < 2; m++) {
            unsigned int p01 = cvt2_fp8(acc[m][n][0], acc[m][n][1]);
            unsigned int p23 = cvt2_fp8(acc[m][n][2], acc[m][n][3]);
            long row = bm + wm * 32 + m * 16 + (lane >> 4) * 4;
            Pk[(row + 0) * 256 + col] = (unsigned char)(p01 & 0xFF);
            Pk[(row + 1) * 256 + col] = (unsigned char)((p01 >> 8) & 0xFF);
            Pk[(row + 2) * 256 + col] = (unsigned char)(p23 & 0xFF);
            Pk[(row + 3) * 256 + col] = (unsigned char)((p23 >> 8) & 0xFF);
        }
    }
}

// --------------------------------- reduce 8 fp8 partials + b1 + tanh -> h (bf16)
__global__ __launch_bounds__(256) void reduce_h_k(const unsigned char* __restrict__ P,
                                                  const float* __restrict__ b1,
                                                  unsigned short* __restrict__ h) {
    const int idx = blockIdx.x * 256 + threadIdx.x;   // 262,144 groups of 8
    float s[8];
#pragma unroll
    for (int e = 0; e < 8; e++) s[e] = 0.f;
#pragma unroll
    for (int kz = 0; kz < SPLITK; kz++) {
        unsigned long long v =
            *(const unsigned long long*)(P + (long)kz * 2097152 + (long)idx * 8);
#pragma unroll
        for (int q = 0; q < 4; q++) {
            f32x2 d = fp8x2_f32((unsigned int)((v >> (16 * q)) & 0xFFFF));
            s[2 * q]     += d[0];
            s[2 * q + 1] += d[1];
        }
    }
    const int cb = (idx & 31) * 8;
    f32x4 bv0 = *(const f32x4*)(b1 + cb);
    f32x4 bv1 = *(const f32x4*)(b1 + cb + 4);
    short8 o;
#pragma unroll
    for (int e = 0; e < 4; e++) o[e]     = (short)f2bf(tanhf(s[e] + bv0[e]));
#pragma unroll
    for (int e = 0; e < 4; e++) o[4 + e] = (short)f2bf(tanhf(s[4 + e] + bv1[e]));
    ((short8*)h)[idx] = o;
}

// ------------------- GEMM2 packed: mlpP[8192,2176] = h @ W2p^T + b2p -> fp8
// BM=128, BN=128, BK=64
__global__ __launch_bounds__(256, 2) void gemm2p_k(const unsigned short* __restrict__ A,
                                                   const unsigned short* __restrict__ B,
                                                   const float* __restrict__ bias,
                                                   unsigned char* __restrict__ C) {
    __shared__ unsigned short As[128 * 64];
    __shared__ unsigned short Bs[128 * 64];
    const int tid  = threadIdx.x;
    const int lane = tid & 63;
    const int w    = tid >> 6;
    const int wm   = w >> 1, wn = w & 1;
    const long bm  = (long)blockIdx.x * 128;
    const long bn  = (long)blockIdx.y * 128;   // < 2176

    f32x4 acc[4][4];
#pragma unroll
    for (int m = 0; m < 4; m++)
#pragma unroll
        for (int n = 0; n < 4; n++) acc[m][n] = (f32x4){0.f, 0.f, 0.f, 0.f};

    const int r0 = tid >> 3;
    const int c0 = (tid & 7) * 8;

    for (int kk = 0; kk < 256; kk += 64) {
#pragma unroll
        for (int i = 0; i < 4; i++) {
            gload_lds16(A + (bm + i * 32 + r0) * 256L + kk + c0,
                        (char*)As + i * 4096 + tid * 16);
            gload_lds16(B + (bn + i * 32 + r0) * 256L + kk + c0,
                        (char*)Bs + i * 4096 + tid * 16);
        }
        __syncthreads();

        short8 af[4][2], bf[4][2];
#pragma unroll
        for (int m = 0; m < 4; m++)
#pragma unroll
            for (int kq = 0; kq < 2; kq++)
                af[m][kq] = *(const short8*)&As[(wm * 64 + m * 16 + (lane & 15)) * 64 +
                                                kq * 32 + (lane >> 4) * 8];
#pragma unroll
        for (int n = 0; n < 4; n++)
#pragma unroll
            for (int kq = 0; kq < 2; kq++)
                bf[n][kq] = *(const short8*)&Bs[(wn * 64 + n * 16 + (lane & 15)) * 64 +
                                                kq * 32 + (lane >> 4) * 8];
#pragma unroll
        for (int m = 0; m < 4; m++)
#pragma unroll
            for (int n = 0; n < 4; n++) {
                acc[m][n] = __builtin_amdgcn_mfma_f32_16x16x32_bf16(af[m][0], bf[n][0],
                                                                    acc[m][n], 0, 0, 0);
                acc[m][n] = __builtin_amdgcn_mfma_f32_16x16x32_bf16(af[m][1], bf[n][1],
                                                                    acc[m][n], 0, 0, 0);
            }
        __syncthreads();
    }

#pragma unroll
    for (int n = 0; n < 4; n++) {
        long col = bn + wn * 64 + n * 16 + (lane & 15);
        float bv = bias[col];
#pragma unroll
        for (int m = 0; m < 4; m++) {
            unsigned int p01 = cvt2_fp8(acc[m][n][0] + bv, acc[m][n][1] + bv);
            unsigned int p23 = cvt2_fp8(acc[m][n][2] + bv, acc[m][n][3] + bv);
            long row = bm + wm * 64 + m * 16 + (lane >> 4) * 4;
            C[(row + 0) * NPACK + col] = (unsigned char)(p01 & 0xFF);
            C[(row + 1) * NPACK + col] = (unsigned char)((p01 >> 8) & 0xFF);
            C[(row + 2) * NPACK + col] = (unsigned char)(p23 & 0xFF);
            C[(row + 3) * NPACK + col] = (unsigned char)((p23 >> 8) & 0xFF);
        }
    }
}

// ---- finalize: early-issued metric/ricci loads; NT loads on single-use streams;
// scatter fp8 mlp -> tri LDS; norms -> adt; out = metric + adt*F_sym (NT store).
__global__ __launch_bounds__(256) void finalize3_k(const float* __restrict__ metric,
                                                   const float* __restrict__ ricci,
                                                   const unsigned char* __restrict__ mlpP,
                                                   float* __restrict__ out) {
    const int b = blockIdx.x;
    const int t = threadIdx.x;
    const long mbase = (long)b * 4096;
    __shared__ float s_f[64 * 65];  // lower-tri values live at [i*65 + j], j<=i
    __shared__ float red[8];
    __shared__ float s_adt;

    // ---- early issue: all global loads for this block, before any LDS phase ----
    const f32x4* met4 = (const f32x4*)(metric + mbase);
    const f32x4* ric4 = (const f32x4*)(ricci + mbase);
    const unsigned char* mp = mlpP + (long)b * NPACK;

    f32x4 mm[4], rr[4];
    unsigned long long v0 = __builtin_nontemporal_load(
        (const unsigned long long*)(mp + t * 8));
    unsigned long long v1 = (t < 4)
        ? __builtin_nontemporal_load((const unsigned long long*)(mp + 2048 + t * 8))
        : 0ull;
#pragma unroll
    for (int k = 0; k < 4; k++) {
        int v = k * 256 + t;
        mm[k] = met4[v];                              // keep L3-cached path
        rr[k] = __builtin_nontemporal_load(&ric4[v]); // single-use: don't pollute L3
    }

    // phase 1: scatter packed mlp (fp8, HW decode) into s_f
#pragma unroll
    for (int q = 0; q < 4; q++) {
        f32x2 d = fp8x2_f32((unsigned int)((v0 >> (16 * q)) & 0xFFFF));
#pragma unroll
        for (int e = 0; e < 2; e++) {
            int p = t * 8 + 2 * q + e, i, j;
            tri_unpack(p, i, j);
            s_f[i * 65 + j] = d[e];
        }
    }
    if (t < 4) {                             // p = 2048 .. 2079
#pragma unroll
        for (int q = 0; q < 4; q++) {
            f32x2 d = fp8x2_f32((unsigned int)((v1 >> (16 * q)) & 0xFFFF));
#pragma unroll
            for (int e = 0; e < 2; e++) {
                int p = 2048 + t * 8 + 2 * q + e, i, j;
                tri_unpack(p, i, j);
                s_f[i * 65 + j] = d[e];
            }
        }
    }
    __syncthreads();

    // phase 2: norms + fold -2*ricci into lower-tri slots (unique owner per slot)
    float msq = 0.f, rsq = 0.f;
#pragma unroll
    for (int k = 0; k < 4; k++) {
        int v = k * 256 + t;
        f32x4 r = rr[k];
        f32x4 m = mm[k];
        msq += m[0]*m[0] + m[1]*m[1] + m[2]*m[2] + m[3]*m[3];
        rsq += r[0]*r[0] + r[1]*r[1] + r[2]*r[2] + r[3]*r[3];
        int e0 = v * 4;
        int i = e0 >> 6, j0 = e0 & 63;
#pragma unroll
        for (int e = 0; e < 4; e++) {
            int j = j0 + e;
            if (j <= i) s_f[i * 65 + j] -= 2.f * r[e];
        }
    }
#pragma unroll
    for (int off = 32; off > 0; off >>= 1) {
        msq += __shfl_down(msq, off);
        rsq += __shfl_down(rsq, off);
    }
    if ((t & 63) == 0) { red[t >> 6] = msq; red[4 + (t >> 6)] = rsq; }
    __syncthreads();
    if (t == 0) {
        float tm = red[0] + red[1] + red[2] + red[3];
        float tr = red[4] + red[5] + red[6] + red[7];
        s_adt = DTC * fminf(1.0f, 0.1f * sqrtf(tm) / (sqrtf(tr) + EPSF));
    }
    __syncthreads();

    // phase 3: out = metric + adt * F[max][min]  (nontemporal store)
    const float adt = s_adt;
    f32x4* out4 = (f32x4*)(out + mbase);
#pragma unroll
    for (int k = 0; k < 4; k++) {
        int v = k * 256 + t;
        int e0 = v * 4;
        int i = e0 >> 6, j0 = e0 & 63;
        f32x4 o;
#pragma unroll
        for (int e = 0; e < 4; e++) {
            int j = j0 + e;
            int mx = i > j ? i : j;
            int mn = i > j ? j : i;
            o[e] = mm[k][e] + adt * s_f[mx * 65 + mn];
        }
        __builtin_nontemporal_store(o, &out4[v]);
    }
}

// ---------------------------------------------------------------------- launcher
extern "C" void kernel_launch(void* const* d_in, const int* in_sizes, int n_in,
                              void* d_out, int out_size, void* d_ws, size_t ws_size,
                              hipStream_t stream) {
    const float* metric = (const float*)d_in[0];  // [8192,64,64]
    const float* ricci  = (const float*)d_in[1];  // [8192,64,64]
    const float* W1     = (const float*)d_in[2];  // [256,4096]
    const float* b1     = (const float*)d_in[3];  // [256]
    const float* W2     = (const float*)d_in[4];  // [4096,256]
    const float* b2     = (const float*)d_in[5];  // [4096]
    float* out = (float*)d_out;

    const int B = 8192;

    char* ws = (char*)d_ws;
    unsigned char*  mlpP = (unsigned char*)(ws);                 // 8192*2176   = 17,825,792
    unsigned short* w1b  = (unsigned short*)(ws + 17825792);     // 2,097,152
    unsigned short* w2p  = (unsigned short*)(ws + 19922944);     // 2176*256*2  = 1,114,112
    float*          b2p  = (float*)(ws + 21037056);              // 2176*4      = 8,704
    unsigned short* hbf  = (unsigned short*)(ws + 21045760);     // 8192*256*2  = 4,194,304
    // split-K fp8 partials live in d_out (dead until finalize): 8*8192*256 = 16.8 MB
    unsigned char* part = (unsigned char*)out;

    // pack/cast weights (W1 cast: blocks 0..1023; W2/b2 tri-pack: blocks 1024..3199)
    pack_k<<<dim3(1024 + NPACK), dim3(256), 0, stream>>>(W1, W2, b2, w1b, w2p, b2p);

    // GEMM1: BM=64 x BN=256(full) x split-K=8 -> fp8 partials in d_out (4 blocks/CU)
    gemm1_k<<<dim3(B / 64, SPLITK), dim3(256), 0, stream>>>(metric, w1b, part);
    // h = tanh(sum partials + b1) -> bf16
    reduce_h_k<<<dim3(B * 256 / 8 / 256), dim3(256), 0, stream>>>(part, b1, hbf);
    // mlpP = h @ W2p^T + b2p -> fp8 packed lower-tri columns
    gemm2p_k<<<dim3(B / 128, NPACK / 128), dim3(256), 0, stream>>>(hbf, w2p, b2p, mlpP);
    // out = metric + adt * sym_lower(-2*ricci + mlp)
    finalize3_k<<<dim3(B), dim3(256), 0, stream>>>(metric, ricci, mlpP, out);

    (void)in_sizes; (void)n_in; (void)out_size; (void)ws_size;
}